// Round 5
// baseline (105.217 us; speedup 1.0000x reference)
//
#include <hip/hip_runtime.h>
#include <math.h>

#define SEQ     1024
#define NBATCH  32
#define NC      256   // num_concept
#define NI      512   // 2*num_concept (inter values)
#define DIM     64
#define JT      64    // j-tile width (one lane per j)
#define NJT     (SEQ / JT)   // 16
#define NWAVE   16           // waves per block (1024 threads)

// ws layout: [0, 1MB) table float2[NI*NC]; [1MB, 1.25MB) partial[2][32][1024]
#define PART_OFF (NI * NC * sizeof(float2))

// -------------------------------------------------------------------------
// Kernel 1: collapse the two einsums into a 512x256 lookup table.
//   tab[x*NC + y] = ( dot(aI[x],aC[y]),
//                     clip(dot(bI[x],bC[y]) + 1, 0, 10) / ln(5) )
// 1/ln5 folded into beta so the hot loop does exp2(-beta' * log2(dt)).
// -------------------------------------------------------------------------
__global__ __launch_bounds__(256) void build_tables(
    const float* __restrict__ aI, const float* __restrict__ aC,
    const float* __restrict__ bI, const float* __restrict__ bC,
    float2* __restrict__ tab)
{
    __shared__ float sA[DIM];
    __shared__ float sB[DIM];
    const int x = blockIdx.x;
    const int t = threadIdx.x;
    if (t < DIM)            sA[t]        = aI[x * DIM + t];
    else if (t < 2 * DIM)   sB[t - DIM]  = bI[x * DIM + (t - DIM)];
    __syncthreads();

    const int y = t;  // 256 threads == NC concepts
    const float4* ca = (const float4*)(aC + y * DIM);
    const float4* cb = (const float4*)(bC + y * DIM);
    float da = 0.f, db = 0.f;
#pragma unroll
    for (int k = 0; k < DIM / 4; ++k) {
        float4 va = ca[k];
        float4 vb = cb[k];
        da += sA[4*k+0]*va.x + sA[4*k+1]*va.y + sA[4*k+2]*va.z + sA[4*k+3]*va.w;
        db += sB[4*k+0]*vb.x + sB[4*k+1]*vb.y + sB[4*k+2]*vb.z + sB[4*k+3]*vb.w;
    }
    const float inv_ln5 = 0.6213349345596119f;  // 1/ln(5)
    float beta = fminf(fmaxf(db + 1.0f, 0.0f), 10.0f) * inv_ln5;
    tab[x * NC + y] = make_float2(da, beta);
}

// -------------------------------------------------------------------------
// Kernel 2: causal cross-effect partial sums.
//   partial[z][b][j] = sum_{i in z-half, i<j} alpha * exp2(-beta' * log2(dt))
// Grid (NBATCH, NJT/2, 2), block 1024 = 16 waves. Block (b,p,z):
//   paired tiles {15-p, p} (perfect balance: 17*32 rows per block),
//   z = which half of each tile's i-range -> 512 blocks = 2 blocks/CU
//   = 8 waves/SIMD (R4 had 4; latency-bound at ~500cyc chains).
// LDS entry packs (row byte-offset, t_i) -> single ds_read_b64 per iter.
// -------------------------------------------------------------------------
__global__ __launch_bounds__(1024) void hawkes_main(
    const int* __restrict__ concept_seq,
    const int* __restrict__ correct_seq, const int* __restrict__ time_seq,
    const float2* __restrict__ tab,
    float* __restrict__ partial)
{
    __shared__ float2 st[SEQ];        // .x = __int_as_float(row byte off), .y = t_i
    __shared__ float  part[NWAVE][JT];

    const int b   = blockIdx.x;
    const int p   = blockIdx.y;          // pair id 0..7
    const int z   = blockIdx.z;          // i-half 0/1
    const int tid = threadIdx.x;
    const int w   = tid >> 6;            // wave id 0..15
    const int l   = tid & 63;            // lane

    const int jt_big   = (NJT - 1) - p;  // 15-p
    const int jt_small = p;
    const int I_big    = (jt_big + 1) * JT;

    // Stage prefix: one entry per thread (I_big <= 1024).
    if (tid < I_big) {
        int c   = concept_seq[b * SEQ + tid];
        int off = (c + (correct_seq[b * SEQ + tid] << 8)) << 11;  // s * NC * 8
        st[tid] = make_float2(__int_as_float(off), (float)time_seq[b * SEQ + tid]);
    }
    __syncthreads();

    const char* tabc = (const char*)tab;

#pragma unroll
    for (int tile = 0; tile < 2; ++tile) {
        const int jt = tile ? jt_small : jt_big;
        const int I  = (jt + 1) * JT;
        const int j  = jt * JT + l;
        const int cj8 = concept_seq[b * SEQ + j] * 8;
        const float tj = st[j].y;

        float acc = 0.0f;
        const int chunk = I >> 5;        // I/2 rows over 16 waves; >= 2
        const int i0 = z * (I >> 1) + w * chunk;
#pragma unroll 4
        for (int i = i0; i < i0 + chunk; ++i) {
            float2 sv = st[i];
            int   off = __float_as_int(sv.x);
            float2 ab = *(const float2*)(tabc + off + cj8);  // (alpha, beta')
            float dt  = fabsf(tj - sv.y);
            float dl  = __builtin_amdgcn_logf(dt + 1e-10f);  // log2
            float e   = __builtin_amdgcn_exp2f(-ab.y * dl);
            // select, NOT multiply-by-mask: masked lanes may hold inf
            // (dt==0 with large beta) and 0*inf would poison the sum.
            acc += (i < j) ? ab.x * e : 0.0f;
        }

        __syncthreads();                 // tile 1: epilogue of tile 0 done
        part[w][l] = acc;
        __syncthreads();

        if (w == 0) {
            float s = 0.0f;
#pragma unroll
            for (int k = 0; k < NWAVE; ++k) s += part[k][l];
            partial[(z * NBATCH + b) * SEQ + j] = s;
        }
    }
}

// -------------------------------------------------------------------------
// Kernel 3: combine halves + bias + sigmoid + [:,1:] slice.
// -------------------------------------------------------------------------
__global__ __launch_bounds__(256) void finalize(
    const float* __restrict__ partial,
    const int* __restrict__ concept_seq, const int* __restrict__ question_seq,
    const float* __restrict__ qbias, const float* __restrict__ cbias,
    float* __restrict__ out)
{
    const int idx = blockIdx.x * 256 + threadIdx.x;   // 32*1024 threads
    const int b = idx >> 10;
    const int j = idx & (SEQ - 1);
    if (j < 1) return;
    float s = partial[b * SEQ + j] + partial[(NBATCH + b) * SEQ + j];
    float zv = qbias[question_seq[b * SEQ + j]] + cbias[concept_seq[b * SEQ + j]] + s;
    float ez = __builtin_amdgcn_exp2f(-zv * 1.4426950408889634f);
    out[b * (SEQ - 1) + (j - 1)] = 1.0f / (1.0f + ez);
}

// -------------------------------------------------------------------------
extern "C" void kernel_launch(void* const* d_in, const int* in_sizes, int n_in,
                              void* d_out, int out_size, void* d_ws, size_t ws_size,
                              hipStream_t stream) {
    const int*   concept_seq  = (const int*)  d_in[0];
    const int*   question_seq = (const int*)  d_in[1];
    const int*   correct_seq  = (const int*)  d_in[2];
    const int*   time_seq     = (const int*)  d_in[3];
    const float* aI           = (const float*)d_in[4];
    const float* aC           = (const float*)d_in[5];
    const float* bI           = (const float*)d_in[6];
    const float* bC           = (const float*)d_in[7];
    const float* qbias        = (const float*)d_in[8];
    const float* cbias        = (const float*)d_in[9];
    float*       out          = (float*)d_out;

    float2* tab     = (float2*)d_ws;                        // 1 MiB
    float*  partial = (float*)((char*)d_ws + PART_OFF);     // 2*32*1024 f32

    build_tables<<<NI, 256, 0, stream>>>(aI, aC, bI, bC, tab);
    hawkes_main<<<dim3(NBATCH, NJT / 2, 2), 1024, 0, stream>>>(
        concept_seq, correct_seq, time_seq, tab, partial);
    finalize<<<(NBATCH * SEQ) / 256, 256, 0, stream>>>(
        partial, concept_seq, question_seq, qbias, cbias, out);
}

// Round 6
// 100.352 us; speedup vs baseline: 1.0485x; 1.0485x over previous
//
#include <hip/hip_runtime.h>
#include <hip/hip_bf16.h>
#include <math.h>

#define SEQ     1024
#define NBATCH  32
#define NC      256   // num_concept
#define NI      512   // 2*num_concept (inter values)
#define DIM     64
#define JT      64    // j-tile width (one lane per j)
#define NJT     (SEQ / JT)   // 16
#define NWAVE   16           // waves per block (1024 threads)

// -------------------------------------------------------------------------
// Kernel 1: collapse the two einsums into a 512x256 lookup table, packed
// bf16x2 (4 B/entry -> 1 KB rows: halves gather line-footprint vs f32x2).
//   tab[x][y] = ( bf16(dot(aI[x],aC[y])),
//                 bf16(clip(dot(bI[x],bC[y])+1, 0, 10) / ln5) )
// alpha/beta ~ 1e-3 scale (N(0,0.01^2) 64-dots): bf16 rel err 0.4% -> per-
// term abs err ~1e-6, harmless vs 0.02 threshold.
// -------------------------------------------------------------------------
__global__ __launch_bounds__(256) void build_tables(
    const float* __restrict__ aI, const float* __restrict__ aC,
    const float* __restrict__ bI, const float* __restrict__ bC,
    __hip_bfloat162* __restrict__ tab)
{
    __shared__ float sA[DIM];
    __shared__ float sB[DIM];
    const int x = blockIdx.x;
    const int t = threadIdx.x;
    if (t < DIM)            sA[t]        = aI[x * DIM + t];
    else if (t < 2 * DIM)   sB[t - DIM]  = bI[x * DIM + (t - DIM)];
    __syncthreads();

    const int y = t;  // 256 threads == NC concepts
    const float4* ca = (const float4*)(aC + y * DIM);
    const float4* cb = (const float4*)(bC + y * DIM);
    float da = 0.f, db = 0.f;
#pragma unroll
    for (int k = 0; k < DIM / 4; ++k) {
        float4 va = ca[k];
        float4 vb = cb[k];
        da += sA[4*k+0]*va.x + sA[4*k+1]*va.y + sA[4*k+2]*va.z + sA[4*k+3]*va.w;
        db += sB[4*k+0]*vb.x + sB[4*k+1]*vb.y + sB[4*k+2]*vb.z + sB[4*k+3]*vb.w;
    }
    const float inv_ln5 = 0.6213349345596119f;  // 1/ln(5)
    float beta = fminf(fmaxf(db + 1.0f, 0.0f), 10.0f) * inv_ln5;
    __hip_bfloat162 v;
    v.x = __float2bfloat16(da);    // low 16
    v.y = __float2bfloat16(beta);  // high 16
    tab[x * NC + y] = v;
}

// -------------------------------------------------------------------------
// Kernel 2: causal cross-effect sums + FUSED epilogue (2 launches total).
//   sum_t[b,j] = sum_{i<j} alpha * exp2(-beta' * log2(|tj-ti|+1e-10))
//   out[b,j-1] = sigmoid(qbias[q_j] + cbias[c_j] + sum_t)
// Grid (NBATCH, NJT/2) = 256 blocks x 1024 thr. Block (b,p): paired tiles
// {15-p, p} -> perfectly balanced 17*64 rows/block.
// R6 gather fix (L2 line amplification was ~2KB/wave-iter = ~16 us):
//   * bf16x2 table: 1KB rows -> ~8x128B lines per gather (2x less L2)
//   * fused prefix loop: i < I_small issues BOTH tiles' gathers on the
//     same row back-to-back -> 2nd is an L1 hit (another ~0.74x)
// Waves take i = w + 16k (stride-16): equal fused/big-only split per wave.
// -------------------------------------------------------------------------
__global__ __launch_bounds__(1024) void hawkes_main(
    const int* __restrict__ concept_seq, const int* __restrict__ question_seq,
    const int* __restrict__ correct_seq, const int* __restrict__ time_seq,
    const __hip_bfloat162* __restrict__ tab,
    const float* __restrict__ qbias, const float* __restrict__ cbias,
    float* __restrict__ out)
{
    __shared__ float2 st[SEQ];          // .x = row byte-offset (as float bits), .y = t_i
    __shared__ float  part[NWAVE][2][JT];

    const int b   = blockIdx.x;
    const int p   = blockIdx.y;          // pair id 0..7
    const int tid = threadIdx.x;
    const int w   = tid >> 6;            // wave id 0..15
    const int l   = tid & 63;            // lane

    const int jtB = (NJT - 1) - p;       // big tile 8..15
    const int jtS = p;                   // small tile 0..7
    const int I_B = (jtB + 1) * JT;
    const int I_S = (jtS + 1) * JT;

    // Stage prefix: one entry per thread (I_B <= 1024). Row stride 1KB.
    if (tid < I_B) {
        int c   = concept_seq[b * SEQ + tid];
        int off = (c + (correct_seq[b * SEQ + tid] << 8)) << 10;  // s * NC * 4
        st[tid] = make_float2(__int_as_float(off), (float)time_seq[b * SEQ + tid]);
    }
    __syncthreads();

    const int   jB   = jtB * JT + l;
    const int   jS   = jtS * JT + l;
    const int   cB4  = concept_seq[b * SEQ + jB] * 4;
    const int   cS4  = concept_seq[b * SEQ + jS] * 4;
    const float tjB  = st[jB].y;
    const float tjS  = st[jS].y;

    const char* tabc = (const char*)tab;
    float accB = 0.0f, accS = 0.0f;

    const int nks = I_S >> 4;            // fused iters per wave  (>=4, mult of 4)
    const int nkb = I_B >> 4;            // total iters per wave

    // ---- fused region: i < I_S, both tiles share the (L1-hot) row ----
#pragma unroll 4
    for (int k = 0; k < nks; ++k) {
        const int i = w + (k << 4);
        float2 sv = st[i];
        const char* row = tabc + __float_as_int(sv.x);
        unsigned uB = *(const unsigned*)(row + cB4);
        unsigned uS = *(const unsigned*)(row + cS4);
        float dlB = __builtin_amdgcn_logf(fabsf(tjB - sv.y) + 1e-10f);
        float dlS = __builtin_amdgcn_logf(fabsf(tjS - sv.y) + 1e-10f);
        float aB  = __uint_as_float(uB << 16);
        float bB  = __uint_as_float(uB & 0xFFFF0000u);
        float aS  = __uint_as_float(uS << 16);
        float bS  = __uint_as_float(uS & 0xFFFF0000u);
        float eB  = __builtin_amdgcn_exp2f(-bB * dlB);
        float eS  = __builtin_amdgcn_exp2f(-bS * dlS);
        // select, NOT multiply-by-mask: dt==0 lanes can make e inf.
        accB += (i < jB) ? aB * eB : 0.0f;
        accS += (i < jS) ? aS * eS : 0.0f;
    }
    // ---- big-only region: I_S <= i < I_B ----
#pragma unroll 4
    for (int k = nks; k < nkb; ++k) {
        const int i = w + (k << 4);
        float2 sv = st[i];
        unsigned uB = *(const unsigned*)(tabc + __float_as_int(sv.x) + cB4);
        float dlB = __builtin_amdgcn_logf(fabsf(tjB - sv.y) + 1e-10f);
        float aB  = __uint_as_float(uB << 16);
        float bB  = __uint_as_float(uB & 0xFFFF0000u);
        accB += (i < jB) ? aB * __builtin_amdgcn_exp2f(-bB * dlB) : 0.0f;
    }

    part[w][0][l] = accB;
    part[w][1][l] = accS;
    __syncthreads();

    // Fused epilogue: wave 0 -> big tile, wave 1 -> small tile.
    if (w < 2) {
        const int j  = (w == 0) ? jB : jS;
        float s = 0.0f;
#pragma unroll
        for (int k = 0; k < NWAVE; ++k) s += part[k][w][l];
        if (j >= 1) {
            float zv = qbias[question_seq[b * SEQ + j]]
                     + cbias[concept_seq[b * SEQ + j]] + s;
            float ez = __builtin_amdgcn_exp2f(-zv * 1.4426950408889634f);
            out[b * (SEQ - 1) + (j - 1)] = 1.0f / (1.0f + ez);
        }
    }
}

// -------------------------------------------------------------------------
extern "C" void kernel_launch(void* const* d_in, const int* in_sizes, int n_in,
                              void* d_out, int out_size, void* d_ws, size_t ws_size,
                              hipStream_t stream) {
    const int*   concept_seq  = (const int*)  d_in[0];
    const int*   question_seq = (const int*)  d_in[1];
    const int*   correct_seq  = (const int*)  d_in[2];
    const int*   time_seq     = (const int*)  d_in[3];
    const float* aI           = (const float*)d_in[4];
    const float* aC           = (const float*)d_in[5];
    const float* bI           = (const float*)d_in[6];
    const float* bC           = (const float*)d_in[7];
    const float* qbias        = (const float*)d_in[8];
    const float* cbias        = (const float*)d_in[9];
    float*       out          = (float*)d_out;

    __hip_bfloat162* tab = (__hip_bfloat162*)d_ws;   // 512 KiB

    build_tables<<<NI, 256, 0, stream>>>(aI, aC, bI, bC, tab);
    hawkes_main<<<dim3(NBATCH, NJT / 2), 1024, 0, stream>>>(
        concept_seq, question_seq, correct_seq, time_seq, tab, qbias, cbias, out);
}